// Round 1
// baseline (523.919 us; speedup 1.0000x reference)
//
#include <hip/hip_runtime.h>

#define N_NODES 50000
#define E_EDGES 800000
#define F_IN    128
#define EDGE_DIM 64
#define H_HEADS 8
#define C_DIM   32
#define HC      256
#define NEG_SLOPE 0.2f
#define NPB 16  // nodes per block in k1

// ---------- K0: fold W_edge [64,256] with att_edge [8,32] -> We_fold [64,8] ----------
__global__ void k0_fold(const float* __restrict__ W_edge, const float* __restrict__ att_edge,
                        float* __restrict__ We_fold) {
    int t = threadIdx.x;          // 0..511
    int d = t >> 3, h = t & 7;
    float s = 0.f;
    #pragma unroll
    for (int c = 0; c < C_DIM; ++c)
        s = fmaf(W_edge[d * HC + h * C_DIM + c], att_edge[h * C_DIM + c], s);
    We_fold[d * H_HEADS + h] = s;
}

// ---------- K1: xs = relu(x) @ W, plus per-node logits a_src, a_dst ----------
__global__ __launch_bounds__(256) void k1_node(const float* __restrict__ x, const float* __restrict__ W,
                                               const float* __restrict__ att_src, const float* __restrict__ att_dst,
                                               float* __restrict__ xs, float* __restrict__ a_src,
                                               float* __restrict__ a_dst) {
    __shared__ float sx[NPB][F_IN];
    int nb = blockIdx.x * NPB;
    int t = threadIdx.x;
    for (int i = t; i < NPB * F_IN; i += 256)
        sx[i >> 7][i & 127] = fmaxf(x[(long)nb * F_IN + i], 0.f);
    __syncthreads();

    float acc[NPB];
    #pragma unroll
    for (int i = 0; i < NPB; ++i) acc[i] = 0.f;

    for (int k = 0; k < F_IN; k += 4) {
        float w0 = W[(k + 0) * HC + t];
        float w1 = W[(k + 1) * HC + t];
        float w2 = W[(k + 2) * HC + t];
        float w3 = W[(k + 3) * HC + t];
        #pragma unroll
        for (int i = 0; i < NPB; ++i) {
            float4 xv = *(const float4*)&sx[i][k];
            acc[i] = fmaf(xv.x, w0, acc[i]);
            acc[i] = fmaf(xv.y, w1, acc[i]);
            acc[i] = fmaf(xv.z, w2, acc[i]);
            acc[i] = fmaf(xv.w, w3, acc[i]);
        }
    }

    int h = t >> 5, c = t & 31;
    float as = att_src[h * C_DIM + c];
    float ad = att_dst[h * C_DIM + c];
    #pragma unroll
    for (int i = 0; i < NPB; ++i) {
        xs[(long)(nb + i) * HC + t] = acc[i];
        float vs = acc[i] * as;
        float vd = acc[i] * ad;
        #pragma unroll
        for (int off = 1; off < 32; off <<= 1) {
            vs += __shfl_xor(vs, off);
            vd += __shfl_xor(vd, off);
        }
        if (c == 0) {
            a_src[(nb + i) * H_HEADS + h] = vs;
            a_dst[(nb + i) * H_HEADS + h] = vd;
        }
    }
}

// ---------- K2: a_edge[e,h] = edge_attr[e,:] @ We_fold[:,h] ----------
__global__ __launch_bounds__(256) void k2_edge(const float* __restrict__ edge_attr,
                                               const float* __restrict__ We_fold,
                                               float* __restrict__ a_edge) {
    __shared__ float se[32 * 65];       // padded: edge e at se[e*65 + d]
    __shared__ float sf[EDGE_DIM * 8];
    int t = threadIdx.x;
    long ebase = (long)blockIdx.x * 32;
    for (int i = t; i < EDGE_DIM * 8; i += 256) sf[i] = We_fold[i];
    for (int i = t; i < 32 * EDGE_DIM; i += 256) {
        int e = i >> 6, d = i & 63;
        se[e * 65 + d] = edge_attr[ebase * EDGE_DIM + i];
    }
    __syncthreads();
    int e = t >> 3, h = t & 7;
    float s = 0.f;
    #pragma unroll
    for (int d = 0; d < EDGE_DIM; ++d)
        s = fmaf(se[e * 65 + d], sf[d * 8 + h], s);
    a_edge[(ebase + e) * 8 + h] = s;
}

// ---------- K_zero: zero the histogram ----------
__global__ void k_zero(int* __restrict__ counts, int n) {
    int i = blockIdx.x * 256 + threadIdx.x;
    if (i < n) counts[i] = 0;
}

// ---------- K3: histogram of dst ----------
__global__ void k3_hist(const int* __restrict__ dst, int* __restrict__ counts) {
    int e = blockIdx.x * 256 + threadIdx.x;
    if (e < E_EDGES) atomicAdd(&counts[dst[e]], 1);
}

// ---------- K4: exclusive scan of counts -> offsets (N+1), copy to cursor ----------
#define SCAN_THREADS 1024
__global__ __launch_bounds__(SCAN_THREADS) void k4_scan(const int* __restrict__ counts,
                                                        int* __restrict__ offsets,
                                                        int* __restrict__ cursor) {
    __shared__ int sums[SCAN_THREADS];
    int t = threadIdx.x;
    const int chunk = (N_NODES + SCAN_THREADS - 1) / SCAN_THREADS;  // 49
    int begin = t * chunk;
    int end = begin + chunk;
    if (end > N_NODES) end = N_NODES;
    int s = 0;
    for (int i = begin; i < end; ++i) s += counts[i];
    sums[t] = s;
    __syncthreads();
    for (int off = 1; off < SCAN_THREADS; off <<= 1) {
        int tmp = (t >= off) ? sums[t - off] : 0;
        __syncthreads();
        sums[t] += tmp;
        __syncthreads();
    }
    int base = sums[t] - s;  // exclusive prefix
    for (int i = begin; i < end; ++i) {
        offsets[i] = base;
        cursor[i] = base;
        base += counts[i];
    }
    if (t == SCAN_THREADS - 1) offsets[N_NODES] = base;
}

// ---------- K5: scatter edge ids into CSR order ----------
__global__ void k5_scatter(const int* __restrict__ dst, int* __restrict__ cursor,
                           int* __restrict__ perm) {
    int e = blockIdx.x * 256 + threadIdx.x;
    if (e < E_EDGES) {
        int pos = atomicAdd(&cursor[dst[e]], 1);
        perm[pos] = e;
    }
}

// ---------- K6: fused per-node segment softmax + weighted aggregation ----------
__global__ __launch_bounds__(256) void k6_aggregate(
    const int* __restrict__ edge_src, const int* __restrict__ perm,
    const int* __restrict__ offsets, const float* __restrict__ a_src,
    const float* __restrict__ a_dst, const float* __restrict__ a_edge,
    const float* __restrict__ xs, const float* __restrict__ bias,
    float* __restrict__ out) {
    __shared__ float s_adst[8];
    __shared__ float s_m[8];
    __shared__ float s_sum[8];
    __shared__ float s_w[32 * 8];
    __shared__ int s_src[32];
    __shared__ float s_wavebuf[4 * 8];

    int n = blockIdx.x;
    int t = threadIdx.x;
    int start = offsets[n], fin = offsets[n + 1];
    if (t < 8) s_adst[t] = a_dst[n * 8 + t];
    __syncthreads();

    int j = t >> 3, h = t & 7;

    // pass 1: per-head max of leaky_relu logits
    float lm = -3.4e38f;
    for (int base = start + j; base < fin; base += 32) {
        int e = perm[base];
        int s = edge_src[e];
        float v = a_src[s * 8 + h] + s_adst[h] + a_edge[(long)e * 8 + h];
        v = (v > 0.f) ? v : NEG_SLOPE * v;
        lm = fmaxf(lm, v);
    }
    lm = fmaxf(lm, __shfl_xor(lm, 8));
    lm = fmaxf(lm, __shfl_xor(lm, 16));
    lm = fmaxf(lm, __shfl_xor(lm, 32));
    if ((t & 63) < 8) s_wavebuf[(t >> 6) * 8 + h] = lm;
    __syncthreads();
    if (t < 8) {
        s_m[t] = fmaxf(fmaxf(s_wavebuf[t], s_wavebuf[8 + t]),
                       fmaxf(s_wavebuf[16 + t], s_wavebuf[24 + t]));
    }
    __syncthreads();

    // pass 2: exp weights + running sum + weighted aggregation (chunks of 32 edges)
    float acc = 0.f;
    float psum = 0.f;
    int h2 = t >> 5;
    float mh = s_m[h];
    for (int base = start; base < fin; base += 32) {
        int nk = fin - base;
        if (nk > 32) nk = 32;
        if (j < nk) {
            int e = perm[base + j];
            int s = edge_src[e];
            if (h == 0) s_src[j] = s;
            float v = a_src[s * 8 + h] + s_adst[h] + a_edge[(long)e * 8 + h];
            v = (v > 0.f) ? v : NEG_SLOPE * v;
            float w = __expf(v - mh);
            psum += w;
            s_w[j * 8 + h] = w;
        }
        __syncthreads();
        for (int jj = 0; jj < nk; ++jj) {
            acc = fmaf(s_w[jj * 8 + h2], xs[(long)s_src[jj] * HC + t], acc);
        }
        __syncthreads();
    }

    psum += __shfl_xor(psum, 8);
    psum += __shfl_xor(psum, 16);
    psum += __shfl_xor(psum, 32);
    if ((t & 63) < 8) s_wavebuf[(t >> 6) * 8 + h] = psum;
    __syncthreads();
    if (t < 8)
        s_sum[t] = s_wavebuf[t] + s_wavebuf[8 + t] + s_wavebuf[16 + t] + s_wavebuf[24 + t];
    __syncthreads();

    float denom = s_sum[h2] + 1e-16f;
    out[(long)n * HC + t] = acc / denom + bias[t];
}

extern "C" void kernel_launch(void* const* d_in, const int* in_sizes, int n_in,
                              void* d_out, int out_size, void* d_ws, size_t ws_size,
                              hipStream_t stream) {
    const float* x         = (const float*)d_in[0];
    const int*   ei        = (const int*)d_in[1];   // [2,E]: src = ei, dst = ei+E
    const float* edge_attr = (const float*)d_in[2];
    const float* W         = (const float*)d_in[3];
    const float* att_src   = (const float*)d_in[4];
    const float* att_dst   = (const float*)d_in[5];
    const float* W_edge    = (const float*)d_in[6];
    const float* att_edge  = (const float*)d_in[7];
    const float* bias      = (const float*)d_in[8];
    float* out = (float*)d_out;

    const int* e_src = ei;
    const int* e_dst = ei + E_EDGES;

    // workspace layout (all 256B aligned sizes)
    char* p = (char*)d_ws;
    float* xs      = (float*)p; p += (size_t)N_NODES * HC * 4;        // 51.2 MB
    float* a_src   = (float*)p; p += (size_t)N_NODES * 8 * 4;         // 1.6 MB
    float* a_dst   = (float*)p; p += (size_t)N_NODES * 8 * 4;         // 1.6 MB
    float* a_edge  = (float*)p; p += (size_t)E_EDGES * 8 * 4;         // 25.6 MB
    float* We_fold = (float*)p; p += 64 * 8 * 4;                      // 2 KB
    int* counts    = (int*)p;   p += (size_t)((N_NODES + 63) / 64) * 64 * 4;
    int* offsets   = (int*)p;   p += (size_t)((N_NODES + 1 + 63) / 64) * 64 * 4;
    int* cursor    = (int*)p;   p += (size_t)((N_NODES + 63) / 64) * 64 * 4;
    int* perm      = (int*)p;   p += (size_t)E_EDGES * 4;             // 3.2 MB

    hipLaunchKernelGGL(k0_fold, dim3(1), dim3(512), 0, stream, W_edge, att_edge, We_fold);
    hipLaunchKernelGGL(k1_node, dim3(N_NODES / NPB), dim3(256), 0, stream,
                       x, W, att_src, att_dst, xs, a_src, a_dst);
    hipLaunchKernelGGL(k2_edge, dim3(E_EDGES / 32), dim3(256), 0, stream,
                       edge_attr, We_fold, a_edge);
    hipLaunchKernelGGL(k_zero, dim3((N_NODES + 255) / 256), dim3(256), 0, stream,
                       counts, N_NODES);
    hipLaunchKernelGGL(k3_hist, dim3((E_EDGES + 255) / 256), dim3(256), 0, stream,
                       e_dst, counts);
    hipLaunchKernelGGL(k4_scan, dim3(1), dim3(SCAN_THREADS), 0, stream,
                       counts, offsets, cursor);
    hipLaunchKernelGGL(k5_scatter, dim3((E_EDGES + 255) / 256), dim3(256), 0, stream,
                       e_dst, cursor, perm);
    hipLaunchKernelGGL(k6_aggregate, dim3(N_NODES), dim3(256), 0, stream,
                       e_src, perm, offsets, a_src, a_dst, a_edge, xs, bias, out);
}

// Round 2
// 343.635 us; speedup vs baseline: 1.5246x; 1.5246x over previous
//
#include <hip/hip_runtime.h>
#include <hip/hip_bf16.h>

#define N_NODES 50000
#define E_EDGES 800000
#define F_IN    128
#define EDGE_DIM 64
#define H_HEADS 8
#define C_DIM   32
#define HC      256
#define NEG_SLOPE 0.2f
#define NPB 16  // nodes per block in k1

// ---------- K0: fold W_edge [64,256] with att_edge [8,32] -> We_fold [64,8] ----------
__global__ void k0_fold(const float* __restrict__ W_edge, const float* __restrict__ att_edge,
                        float* __restrict__ We_fold) {
    int t = threadIdx.x;          // 0..511
    int d = t >> 3, h = t & 7;
    float s = 0.f;
    #pragma unroll
    for (int c = 0; c < C_DIM; ++c)
        s = fmaf(W_edge[d * HC + h * C_DIM + c], att_edge[h * C_DIM + c], s);
    We_fold[d * H_HEADS + h] = s;
}

// ---------- K_zero: zero counts + global cursor ----------
__global__ void k_zero(int* __restrict__ counts, int* __restrict__ gcur) {
    int i = blockIdx.x * 256 + threadIdx.x;
    if (i < N_NODES) counts[i] = 0;
    if (i == 0) *gcur = 0;
}

// ---------- K1: xs = relu(x) @ W (bf16 out), plus per-node logits a_src, a_dst ----------
__global__ __launch_bounds__(256) void k1_node(const float* __restrict__ x, const float* __restrict__ W,
                                               const float* __restrict__ att_src, const float* __restrict__ att_dst,
                                               __hip_bfloat16* __restrict__ xs_bf, float* __restrict__ a_src,
                                               float* __restrict__ a_dst) {
    __shared__ float sx[NPB][F_IN];
    int nb = blockIdx.x * NPB;
    int t = threadIdx.x;
    for (int i = t; i < NPB * F_IN; i += 256)
        sx[i >> 7][i & 127] = fmaxf(x[(long)nb * F_IN + i], 0.f);
    __syncthreads();

    float acc[NPB];
    #pragma unroll
    for (int i = 0; i < NPB; ++i) acc[i] = 0.f;

    for (int k = 0; k < F_IN; k += 4) {
        float w0 = W[(k + 0) * HC + t];
        float w1 = W[(k + 1) * HC + t];
        float w2 = W[(k + 2) * HC + t];
        float w3 = W[(k + 3) * HC + t];
        #pragma unroll
        for (int i = 0; i < NPB; ++i) {
            float4 xv = *(const float4*)&sx[i][k];
            acc[i] = fmaf(xv.x, w0, acc[i]);
            acc[i] = fmaf(xv.y, w1, acc[i]);
            acc[i] = fmaf(xv.z, w2, acc[i]);
            acc[i] = fmaf(xv.w, w3, acc[i]);
        }
    }

    int h = t >> 5, c = t & 31;
    float as = att_src[h * C_DIM + c];
    float ad = att_dst[h * C_DIM + c];
    #pragma unroll
    for (int i = 0; i < NPB; ++i) {
        xs_bf[(long)(nb + i) * HC + t] = __float2bfloat16(acc[i]);
        float vs = acc[i] * as;
        float vd = acc[i] * ad;
        #pragma unroll
        for (int off = 1; off < 32; off <<= 1) {
            vs += __shfl_xor(vs, off);
            vd += __shfl_xor(vd, off);
        }
        if (c == 0) {
            a_src[(nb + i) * H_HEADS + h] = vs;
            a_dst[(nb + i) * H_HEADS + h] = vd;
        }
    }
}

// ---------- K2: a_edge[e,h] = edge_attr[e,:] @ We_fold[:,h]  + fused dst histogram ----------
__global__ __launch_bounds__(256) void k2_edge(const float* __restrict__ edge_attr,
                                               const float* __restrict__ We_fold,
                                               const int* __restrict__ dst,
                                               int* __restrict__ counts,
                                               float* __restrict__ a_edge) {
    __shared__ float se[32 * 65];       // padded: edge e at se[e*65 + d]
    __shared__ float sf[EDGE_DIM * 8];
    int t = threadIdx.x;
    long ebase = (long)blockIdx.x * 32;
    if (t < 32) atomicAdd(&counts[dst[ebase + t]], 1);
    for (int i = t; i < EDGE_DIM * 8; i += 256) sf[i] = We_fold[i];
    for (int i = t; i < 32 * EDGE_DIM; i += 256) {
        int e = i >> 6, d = i & 63;
        se[e * 65 + d] = edge_attr[ebase * EDGE_DIM + i];
    }
    __syncthreads();
    int e = t >> 3, h = t & 7;
    float s = 0.f;
    #pragma unroll
    for (int d = 0; d < EDGE_DIM; ++d)
        s = fmaf(se[e * 65 + d], sf[d * 8 + h], s);
    a_edge[(ebase + e) * 8 + h] = s;
}

// ---------- K4: allocate CSR segments (order-free): starts/cursor via wave scan ----------
__global__ __launch_bounds__(256) void k4_alloc(const int* __restrict__ counts,
                                                int* __restrict__ starts,
                                                int* __restrict__ cursor,
                                                int* __restrict__ gcur) {
    int n = blockIdx.x * 256 + threadIdx.x;
    int c = (n < N_NODES) ? counts[n] : 0;
    int incl = c;
    #pragma unroll
    for (int off = 1; off < 64; off <<= 1) {
        int u = __shfl_up(incl, off);
        if ((threadIdx.x & 63) >= off) incl += u;
    }
    int total = __shfl(incl, 63);
    int wavebase = 0;
    if ((threadIdx.x & 63) == 63) wavebase = atomicAdd(gcur, total);
    wavebase = __shfl(wavebase, 63);
    if (n < N_NODES) {
        int st = wavebase + incl - c;
        starts[n] = st;
        cursor[n] = st;
    }
}

// ---------- K5: per-edge exp-weight + scatter into CSR order ----------
__global__ __launch_bounds__(256) void k5_build(const int* __restrict__ src,
                                                const int* __restrict__ dst,
                                                const float* __restrict__ a_src,
                                                const float* __restrict__ a_dst,
                                                const float* __restrict__ a_edge,
                                                int* __restrict__ cursor,
                                                float* __restrict__ w_perm,
                                                int* __restrict__ src_perm) {
    int e = blockIdx.x * 256 + threadIdx.x;
    if (e >= E_EDGES) return;
    int s = src[e], d = dst[e];
    int pos = atomicAdd(&cursor[d], 1);
    float4 as0 = *(const float4*)&a_src[(long)s * 8];
    float4 as1 = *(const float4*)&a_src[(long)s * 8 + 4];
    float4 ad0 = *(const float4*)&a_dst[(long)d * 8];
    float4 ad1 = *(const float4*)&a_dst[(long)d * 8 + 4];
    float4 ae0 = *(const float4*)&a_edge[(long)e * 8];
    float4 ae1 = *(const float4*)&a_edge[(long)e * 8 + 4];
    float4 w0, w1;
    #define LRE(a, b, c) ({ float v_ = (a) + (b) + (c); v_ = (v_ > 0.f) ? v_ : NEG_SLOPE * v_; __expf(v_); })
    w0.x = LRE(as0.x, ad0.x, ae0.x);
    w0.y = LRE(as0.y, ad0.y, ae0.y);
    w0.z = LRE(as0.z, ad0.z, ae0.z);
    w0.w = LRE(as0.w, ad0.w, ae0.w);
    w1.x = LRE(as1.x, ad1.x, ae1.x);
    w1.y = LRE(as1.y, ad1.y, ae1.y);
    w1.z = LRE(as1.z, ad1.z, ae1.z);
    w1.w = LRE(as1.w, ad1.w, ae1.w);
    #undef LRE
    *(float4*)&w_perm[(long)pos * 8]     = w0;
    *(float4*)&w_perm[(long)pos * 8 + 4] = w1;
    src_perm[pos] = s;
}

// ---------- K6: per-node streaming softmax-normalize + weighted aggregation ----------
__global__ __launch_bounds__(256) void k6_aggregate(
    const int* __restrict__ starts, const int* __restrict__ counts,
    const float* __restrict__ w_perm, const int* __restrict__ src_perm,
    const __hip_bfloat16* __restrict__ xs, const float* __restrict__ bias,
    float* __restrict__ out) {
    __shared__ float s_w[32 * 8];
    __shared__ int s_src[32];
    __shared__ float s_wavebuf[4 * 8];
    __shared__ float s_sum[8];

    int n = blockIdx.x;
    int t = threadIdx.x;
    int start = starts[n];
    int fin = start + counts[n];
    int j = t >> 3, h = t & 7, h2 = t >> 5;

    float acc = 0.f;
    float psum = 0.f;
    for (int base = start; base < fin; base += 32) {
        int nk = fin - base;
        if (nk > 32) nk = 32;
        if (j < nk) {
            float w = w_perm[(long)(base + j) * 8 + h];
            s_w[j * 8 + h] = w;
            psum += w;
        }
        if (t < nk) s_src[t] = src_perm[base + t];
        __syncthreads();
        if (nk == 32) {
            #pragma unroll
            for (int jj = 0; jj < 32; ++jj)
                acc = fmaf(s_w[jj * 8 + h2],
                           __bfloat162float(xs[(long)s_src[jj] * HC + t]), acc);
        } else {
            for (int jj = 0; jj < nk; ++jj)
                acc = fmaf(s_w[jj * 8 + h2],
                           __bfloat162float(xs[(long)s_src[jj] * HC + t]), acc);
        }
        __syncthreads();
    }

    psum += __shfl_xor(psum, 8);
    psum += __shfl_xor(psum, 16);
    psum += __shfl_xor(psum, 32);
    if ((t & 63) < 8) s_wavebuf[(t >> 6) * 8 + h] = psum;
    __syncthreads();
    if (t < 8)
        s_sum[t] = s_wavebuf[t] + s_wavebuf[8 + t] + s_wavebuf[16 + t] + s_wavebuf[24 + t];
    __syncthreads();

    out[(long)n * HC + t] = acc / (s_sum[h2] + 1e-16f) + bias[t];
}

extern "C" void kernel_launch(void* const* d_in, const int* in_sizes, int n_in,
                              void* d_out, int out_size, void* d_ws, size_t ws_size,
                              hipStream_t stream) {
    const float* x         = (const float*)d_in[0];
    const int*   ei        = (const int*)d_in[1];   // [2,E]: src = ei, dst = ei+E
    const float* edge_attr = (const float*)d_in[2];
    const float* W         = (const float*)d_in[3];
    const float* att_src   = (const float*)d_in[4];
    const float* att_dst   = (const float*)d_in[5];
    const float* W_edge    = (const float*)d_in[6];
    const float* att_edge  = (const float*)d_in[7];
    const float* bias      = (const float*)d_in[8];
    float* out = (float*)d_out;

    const int* e_src = ei;
    const int* e_dst = ei + E_EDGES;

    // workspace layout (256B-aligned chunks)
    char* p = (char*)d_ws;
    __hip_bfloat16* xs_bf = (__hip_bfloat16*)p; p += (size_t)N_NODES * HC * 2;  // 25.6 MB
    float* a_src   = (float*)p; p += (size_t)N_NODES * 8 * 4;                   // 1.6 MB
    float* a_dst   = (float*)p; p += (size_t)N_NODES * 8 * 4;                   // 1.6 MB
    float* a_edge  = (float*)p; p += (size_t)E_EDGES * 8 * 4;                   // 25.6 MB
    float* We_fold = (float*)p; p += 64 * 8 * 4;                                // 2 KB
    int* counts    = (int*)p;   p += (size_t)((N_NODES + 63) / 64) * 64 * 4;
    int* starts    = (int*)p;   p += (size_t)((N_NODES + 63) / 64) * 64 * 4;
    int* cursor    = (int*)p;   p += (size_t)((N_NODES + 63) / 64) * 64 * 4;
    int* gcur      = (int*)p;   p += 256;
    float* w_perm  = (float*)p; p += (size_t)E_EDGES * 8 * 4;                   // 25.6 MB
    int* src_perm  = (int*)p;   p += (size_t)E_EDGES * 4;                       // 3.2 MB

    hipLaunchKernelGGL(k0_fold, dim3(1), dim3(512), 0, stream, W_edge, att_edge, We_fold);
    hipLaunchKernelGGL(k_zero, dim3((N_NODES + 255) / 256), dim3(256), 0, stream, counts, gcur);
    hipLaunchKernelGGL(k1_node, dim3(N_NODES / NPB), dim3(256), 0, stream,
                       x, W, att_src, att_dst, xs_bf, a_src, a_dst);
    hipLaunchKernelGGL(k2_edge, dim3(E_EDGES / 32), dim3(256), 0, stream,
                       edge_attr, We_fold, e_dst, counts, a_edge);
    hipLaunchKernelGGL(k4_alloc, dim3((N_NODES + 255) / 256), dim3(256), 0, stream,
                       counts, starts, cursor, gcur);
    hipLaunchKernelGGL(k5_build, dim3((E_EDGES + 255) / 256), dim3(256), 0, stream,
                       e_src, e_dst, a_src, a_dst, a_edge, cursor, w_perm, src_perm);
    hipLaunchKernelGGL(k6_aggregate, dim3(N_NODES), dim3(256), 0, stream,
                       starts, counts, w_perm, src_perm, xs_bf, bias, out);
}

// Round 5
// 268.883 us; speedup vs baseline: 1.9485x; 1.2780x over previous
//
#include <hip/hip_runtime.h>

#define N_NODES 50000
#define E_EDGES 800000
#define F_IN    128
#define EDGE_DIM 64
#define HC      256
#define NEG_SLOPE 0.2f

typedef __attribute__((ext_vector_type(8))) short short8;
typedef __attribute__((ext_vector_type(4))) float f32x4;

__device__ __forceinline__ unsigned short f2bf(float f) {
    unsigned u = __builtin_bit_cast(unsigned, f);
    u += 0x7fffu + ((u >> 16) & 1u);
    return (unsigned short)(u >> 16);
}
__device__ __forceinline__ float bf2f(unsigned short b) {
    return __builtin_bit_cast(float, (unsigned)b << 16);
}

// ---------- K_pre: zero counts/gcur, W_T bf16 [256][128], WaT bf16 [16][128], We_fold ----------
__global__ __launch_bounds__(256) void k_pre(const float* __restrict__ W,
        const float* __restrict__ att_src, const float* __restrict__ att_dst,
        const float* __restrict__ W_edge, const float* __restrict__ att_edge,
        unsigned short* __restrict__ W_T, unsigned short* __restrict__ WaT,
        float* __restrict__ We_fold, int* __restrict__ counts, int* __restrict__ gcur) {
    int idx = blockIdx.x * 256 + threadIdx.x;
    if (idx < N_NODES) counts[idx] = 0;
    if (idx == 0) *gcur = 0;
    if (idx < 32768) {
        int n = idx >> 7, k = idx & 127;
        W_T[n * 128 + k] = f2bf(W[k * 256 + n]);
    }
    if (idx < 2048) {
        int col = idx & 15, k = idx >> 4;
        const float* att = (col < 8) ? att_src : att_dst;
        int h = col & 7;
        float s = 0.f;
        #pragma unroll
        for (int c = 0; c < 32; ++c)
            s = fmaf(W[k * 256 + h * 32 + c], att[h * 32 + c], s);
        WaT[col * 128 + k] = f2bf(s);
    }
    if (idx < 512) {
        int d = idx >> 3, h = idx & 7;
        float s = 0.f;
        #pragma unroll
        for (int c = 0; c < 32; ++c)
            s = fmaf(W_edge[d * 256 + h * 32 + c], att_edge[h * 32 + c], s);
        We_fold[d * 8 + h] = s;
    }
}

// ---------- K1: xs = bf16MFMA(relu(x) @ W), a_src/a_dst via folded 17th tile ----------
#define NT_TILES 782
#define K1_GRID 512
__global__ __launch_bounds__(256, 2) void k1_mfma(const float* __restrict__ x,
        const unsigned short* __restrict__ W_T, const unsigned short* __restrict__ WaT,
        unsigned short* __restrict__ xs, float* __restrict__ a_src, float* __restrict__ a_dst) {
    __shared__ unsigned short sB[256 * 128];   // 64 KB, XOR-swizzled 16B granules
    __shared__ unsigned short sA[64 * 128];    // 16 KB
    int t = threadIdx.x;
    // stage B (all of W_T): 256 rows x 16 granules = 4096 granules, coalesced 16B
    for (int G = t; G < 4096; G += 256) {
        int n = G >> 4, gi = G & 15;
        *(int4*)&sB[(n * 16 + (gi ^ (n & 7))) * 8] = *(const int4*)&W_T[n * 128 + gi * 8];
    }
    int lane = t & 63, w = t >> 6, mr = lane & 15, g = lane >> 4;
    // Wa fragments from global (4 KB, L1-resident)
    short8 wa[4];
    #pragma unroll
    for (int ks = 0; ks < 4; ++ks)
        wa[ks] = *(const short8*)&WaT[mr * 128 + ks * 32 + g * 8];

    bool first = true;
    for (int rt = blockIdx.x; rt < NT_TILES; rt += K1_GRID) {
        if (!first) __syncthreads();
        first = false;
        // stage A: 64 rows x 128 cols, relu+cvt, swizzled
        for (int G = t; G < 1024; G += 256) {
            int r = G >> 4, gi = G & 15;
            int node = rt * 64 + r;
            unsigned short pk[8];
            if (node < N_NODES) {
                const float* xp = &x[(long)node * 128 + gi * 8];
                #pragma unroll
                for (int jj = 0; jj < 8; ++jj) pk[jj] = f2bf(fmaxf(xp[jj], 0.f));
            } else {
                #pragma unroll
                for (int jj = 0; jj < 8; ++jj) pk[jj] = 0;
            }
            *(int4*)&sA[(r * 16 + (gi ^ (r & 7))) * 8] = *(int4*)pk;
        }
        __syncthreads();

        f32x4 acc[17];
        #pragma unroll
        for (int i = 0; i < 17; ++i) acc[i] = (f32x4){0.f, 0.f, 0.f, 0.f};

        int r16 = w * 16 + mr;
        #pragma unroll
        for (int ks = 0; ks < 4; ++ks) {
            int pos = (ks * 4 + g) ^ (mr & 7);
            short8 a = *(const short8*)&sA[(r16 * 16 + pos) * 8];
            #pragma unroll
            for (int nt = 0; nt < 16; ++nt) {
                short8 b = *(const short8*)&sB[((nt * 16 + mr) * 16 + pos) * 8];
                acc[nt] = __builtin_amdgcn_mfma_f32_16x16x32_bf16(a, b, acc[nt], 0, 0, 0);
            }
            acc[16] = __builtin_amdgcn_mfma_f32_16x16x32_bf16(a, wa[ks], acc[16], 0, 0, 0);
        }

        // epilogue: C layout col=lane&15, row=(lane>>4)*4+r
        #pragma unroll
        for (int r = 0; r < 4; ++r) {
            int node = rt * 64 + w * 16 + g * 4 + r;
            if (node < N_NODES) {
                #pragma unroll
                for (int nt = 0; nt < 16; ++nt)
                    xs[(long)node * 256 + nt * 16 + mr] = f2bf(acc[nt][r]);
                if (mr < 8) a_src[node * 8 + mr]       = acc[16][r];
                else        a_dst[node * 8 + (mr - 8)] = acc[16][r];
            }
        }
    }
}

// ---------- K2: a_edge = edge_attr @ We_fold + fused dst histogram ----------
__global__ __launch_bounds__(256) void k2_edge(const float4* __restrict__ edge_attr4,
                                               const float* __restrict__ We_fold,
                                               const int* __restrict__ dst,
                                               int* __restrict__ counts,
                                               float* __restrict__ a_edge) {
    __shared__ float se[32 * 65];
    __shared__ float sf[EDGE_DIM * 8];
    int t = threadIdx.x;
    long ebase = (long)blockIdx.x * 32;
    if (t < 32) atomicAdd(&counts[dst[ebase + t]], 1);
    for (int i = t; i < EDGE_DIM * 8; i += 256) sf[i] = We_fold[i];
    for (int i = t; i < 512; i += 256) {
        float4 v = edge_attr4[ebase * 16 + i];
        int e = i >> 4, d4 = (i & 15) * 4;
        float* dp = &se[e * 65 + d4];
        dp[0] = v.x; dp[1] = v.y; dp[2] = v.z; dp[3] = v.w;
    }
    __syncthreads();
    int e = t >> 3, h = t & 7;
    float s = 0.f;
    #pragma unroll
    for (int d = 0; d < EDGE_DIM; ++d)
        s = fmaf(se[e * 65 + d], sf[d * 8 + h], s);
    a_edge[(ebase + e) * 8 + h] = s;
}

// ---------- K4: allocate CSR segments (order-free) via wave scan ----------
__global__ __launch_bounds__(256) void k4_alloc(const int* __restrict__ counts,
                                                int* __restrict__ starts,
                                                int* __restrict__ cursor,
                                                int* __restrict__ gcur) {
    int n = blockIdx.x * 256 + threadIdx.x;
    int c = (n < N_NODES) ? counts[n] : 0;
    int incl = c;
    #pragma unroll
    for (int off = 1; off < 64; off <<= 1) {
        int u = __shfl_up(incl, off);
        if ((threadIdx.x & 63) >= off) incl += u;
    }
    int total = __shfl(incl, 63);
    int wavebase = 0;
    if ((threadIdx.x & 63) == 63) wavebase = atomicAdd(gcur, total);
    wavebase = __shfl(wavebase, 63);
    if (n < N_NODES) {
        int st = wavebase + incl - c;
        starts[n] = st;
        cursor[n] = st;
    }
}

// ---------- K5: scatter {edge,src} pairs into CSR order ----------
__global__ __launch_bounds__(256) void k5_scatter(const int* __restrict__ src,
                                                  const int* __restrict__ dst,
                                                  int* __restrict__ cursor,
                                                  int2* __restrict__ pair_perm) {
    int e = blockIdx.x * 256 + threadIdx.x;
    if (e < E_EDGES) {
        int d = dst[e];
        int pos = atomicAdd(&cursor[d], 1);
        pair_perm[pos] = make_int2(e, src[e]);
    }
}

// ---------- K6: per-node weight computation + softmax-normalize + aggregation ----------
__global__ __launch_bounds__(256) void k6_aggregate(
    const int* __restrict__ starts, const int* __restrict__ counts,
    const int2* __restrict__ pair_perm,
    const float* __restrict__ a_src, const float* __restrict__ a_dst,
    const float* __restrict__ a_edge,
    const unsigned short* __restrict__ xs, const float* __restrict__ bias,
    float* __restrict__ out) {
    __shared__ float s_w[32 * 8];
    __shared__ int s_src[32];
    __shared__ float s_wavebuf[4 * 8];
    __shared__ float s_sum[8];

    int n = blockIdx.x;
    int t = threadIdx.x;
    int start = starts[n];
    int cnt = counts[n];
    int j = t >> 3, h = t & 7, h2 = t >> 5;
    float adh = a_dst[n * 8 + h];

    float acc = 0.f, psum = 0.f;
    for (int base = 0; base < cnt; base += 32) {
        int nk = cnt - base; if (nk > 32) nk = 32;
        if (j < nk) {
            int2 pr = pair_perm[start + base + j];
            if (h == 0) s_src[j] = pr.y;
            float v = a_src[pr.y * 8 + h] + adh + a_edge[(long)pr.x * 8 + h];
            v = (v > 0.f) ? v : NEG_SLOPE * v;
            float wv = __expf(v);
            psum += wv;
            s_w[j * 8 + h] = wv;
        }
        __syncthreads();
        for (int jj = 0; jj < nk; ++jj)
            acc = fmaf(s_w[jj * 8 + h2], bf2f(xs[(long)s_src[jj] * HC + t]), acc);
        __syncthreads();
    }
    psum += __shfl_xor(psum, 8);
    psum += __shfl_xor(psum, 16);
    psum += __shfl_xor(psum, 32);
    if ((t & 63) < 8) s_wavebuf[(t >> 6) * 8 + h] = psum;
    __syncthreads();
    if (t < 8) s_sum[t] = s_wavebuf[t] + s_wavebuf[8 + t] + s_wavebuf[16 + t] + s_wavebuf[24 + t];
    __syncthreads();
    out[(long)n * HC + t] = acc / (s_sum[h2] + 1e-16f) + bias[t];
}

extern "C" void kernel_launch(void* const* d_in, const int* in_sizes, int n_in,
                              void* d_out, int out_size, void* d_ws, size_t ws_size,
                              hipStream_t stream) {
    const float* x         = (const float*)d_in[0];
    const int*   ei        = (const int*)d_in[1];   // [2,E]: src = ei, dst = ei+E
    const float* edge_attr = (const float*)d_in[2];
    const float* W         = (const float*)d_in[3];
    const float* att_src   = (const float*)d_in[4];
    const float* att_dst   = (const float*)d_in[5];
    const float* W_edge    = (const float*)d_in[6];
    const float* att_edge  = (const float*)d_in[7];
    const float* bias      = (const float*)d_in[8];
    float* out = (float*)d_out;

    const int* e_src = ei;
    const int* e_dst = ei + E_EDGES;

    char* p = (char*)d_ws;
    unsigned short* xs = (unsigned short*)p; p += (size_t)N_NODES * HC * 2;    // 25.6 MB
    float* a_src   = (float*)p; p += (size_t)N_NODES * 8 * 4;                  // 1.6 MB
    float* a_dst   = (float*)p; p += (size_t)N_NODES * 8 * 4;                  // 1.6 MB
    float* a_edge  = (float*)p; p += (size_t)E_EDGES * 8 * 4;                  // 25.6 MB
    int2*  pair_perm = (int2*)p; p += (size_t)E_EDGES * 8;                     // 6.4 MB
    unsigned short* W_T  = (unsigned short*)p; p += 32768 * 2;                 // 64 KB
    unsigned short* WaT  = (unsigned short*)p; p += 2048 * 2;                  // 4 KB
    float* We_fold = (float*)p; p += 512 * 4;                                  // 2 KB
    int* counts    = (int*)p;   p += 200192;
    int* starts    = (int*)p;   p += 200192;
    int* cursor    = (int*)p;   p += 200192;
    int* gcur      = (int*)p;   p += 256;

    hipLaunchKernelGGL(k_pre, dim3(196), dim3(256), 0, stream,
                       W, att_src, att_dst, W_edge, att_edge, W_T, WaT, We_fold, counts, gcur);
    hipLaunchKernelGGL(k1_mfma, dim3(K1_GRID), dim3(256), 0, stream,
                       x, W_T, WaT, xs, a_src, a_dst);
    hipLaunchKernelGGL(k2_edge, dim3(E_EDGES / 32), dim3(256), 0, stream,
                       (const float4*)edge_attr, We_fold, e_dst, counts, a_edge);
    hipLaunchKernelGGL(k4_alloc, dim3(196), dim3(256), 0, stream,
                       counts, starts, cursor, gcur);
    hipLaunchKernelGGL(k5_scatter, dim3(E_EDGES / 256), dim3(256), 0, stream,
                       e_src, e_dst, cursor, pair_perm);
    hipLaunchKernelGGL(k6_aggregate, dim3(N_NODES), dim3(256), 0, stream,
                       starts, counts, pair_perm, a_src, a_dst, a_edge, xs, bias, out);
}

// Round 6
// 227.053 us; speedup vs baseline: 2.3075x; 1.1842x over previous
//
#include <hip/hip_runtime.h>

#define N_NODES 50000
#define E_EDGES 800000
#define F_IN    128
#define EDGE_DIM 64
#define HC      256
#define NEG_SLOPE 0.2f

typedef __attribute__((ext_vector_type(8))) short short8;
typedef __attribute__((ext_vector_type(4))) float f32x4;

__device__ __forceinline__ unsigned short f2bf(float f) {
    unsigned u = __builtin_bit_cast(unsigned, f);
    u += 0x7fffu + ((u >> 16) & 1u);
    return (unsigned short)(u >> 16);
}
__device__ __forceinline__ float bf2f(unsigned short b) {
    return __builtin_bit_cast(float, (unsigned)b << 16);
}

// ---------- K_pre: zero counts/gcur, W_T bf16 [256][128], WaT bf16 [16][128], We_fold ----------
__global__ __launch_bounds__(256) void k_pre(const float* __restrict__ W,
        const float* __restrict__ att_src, const float* __restrict__ att_dst,
        const float* __restrict__ W_edge, const float* __restrict__ att_edge,
        unsigned short* __restrict__ W_T, unsigned short* __restrict__ WaT,
        float* __restrict__ We_fold, int* __restrict__ counts, int* __restrict__ gcur) {
    int idx = blockIdx.x * 256 + threadIdx.x;
    if (idx < N_NODES) counts[idx] = 0;
    if (idx == 0) *gcur = 0;
    if (idx < 32768) {
        int n = idx >> 7, k = idx & 127;
        W_T[n * 128 + k] = f2bf(W[k * 256 + n]);
    }
    if (idx < 2048) {
        int col = idx & 15, k = idx >> 4;
        const float* att = (col < 8) ? att_src : att_dst;
        int h = col & 7;
        float s = 0.f;
        #pragma unroll
        for (int c = 0; c < 32; ++c)
            s = fmaf(W[k * 256 + h * 32 + c], att[h * 32 + c], s);
        WaT[col * 128 + k] = f2bf(s);
    }
    if (idx < 512) {
        int d = idx >> 3, h = idx & 7;
        float s = 0.f;
        #pragma unroll
        for (int c = 0; c < 32; ++c)
            s = fmaf(W_edge[d * 256 + h * 32 + c], att_edge[h * 32 + c], s);
        We_fold[d * 8 + h] = s;
    }
}

// ---------- K_hist: dst histogram ----------
__global__ void k_hist(const int* __restrict__ dst, int* __restrict__ counts) {
    int e = blockIdx.x * 256 + threadIdx.x;
    if (e < E_EDGES) atomicAdd(&counts[dst[e]], 1);
}

// ---------- K1: xs = bf16MFMA(relu(x) @ W), a_src/a_dst via folded 17th tile ----------
#define NT_TILES 782
#define K1_GRID 512
__global__ __launch_bounds__(256, 2) void k1_mfma(const float* __restrict__ x,
        const unsigned short* __restrict__ W_T, const unsigned short* __restrict__ WaT,
        unsigned short* __restrict__ xs, float* __restrict__ a_src, float* __restrict__ a_dst) {
    __shared__ unsigned short sB[256 * 128];   // 64 KB, XOR-swizzled 16B granules
    __shared__ unsigned short sA[64 * 128];    // 16 KB
    int t = threadIdx.x;
    for (int G = t; G < 4096; G += 256) {
        int n = G >> 4, gi = G & 15;
        *(int4*)&sB[(n * 16 + (gi ^ (n & 7))) * 8] = *(const int4*)&W_T[n * 128 + gi * 8];
    }
    int lane = t & 63, w = t >> 6, mr = lane & 15, g = lane >> 4;
    short8 wa[4];
    #pragma unroll
    for (int ks = 0; ks < 4; ++ks)
        wa[ks] = *(const short8*)&WaT[mr * 128 + ks * 32 + g * 8];

    bool first = true;
    for (int rt = blockIdx.x; rt < NT_TILES; rt += K1_GRID) {
        if (!first) __syncthreads();
        first = false;
        for (int G = t; G < 1024; G += 256) {
            int r = G >> 4, gi = G & 15;
            int node = rt * 64 + r;
            unsigned short pk[8];
            if (node < N_NODES) {
                const float* xp = &x[(long)node * 128 + gi * 8];
                #pragma unroll
                for (int jj = 0; jj < 8; ++jj) pk[jj] = f2bf(fmaxf(xp[jj], 0.f));
            } else {
                #pragma unroll
                for (int jj = 0; jj < 8; ++jj) pk[jj] = 0;
            }
            *(int4*)&sA[(r * 16 + (gi ^ (r & 7))) * 8] = *(int4*)pk;
        }
        __syncthreads();

        f32x4 acc[17];
        #pragma unroll
        for (int i = 0; i < 17; ++i) acc[i] = (f32x4){0.f, 0.f, 0.f, 0.f};

        int r16 = w * 16 + mr;
        #pragma unroll
        for (int ks = 0; ks < 4; ++ks) {
            int pos = (ks * 4 + g) ^ (mr & 7);
            short8 a = *(const short8*)&sA[(r16 * 16 + pos) * 8];
            #pragma unroll
            for (int nt = 0; nt < 16; ++nt) {
                short8 b = *(const short8*)&sB[((nt * 16 + mr) * 16 + pos) * 8];
                acc[nt] = __builtin_amdgcn_mfma_f32_16x16x32_bf16(a, b, acc[nt], 0, 0, 0);
            }
            acc[16] = __builtin_amdgcn_mfma_f32_16x16x32_bf16(a, wa[ks], acc[16], 0, 0, 0);
        }

        #pragma unroll
        for (int r = 0; r < 4; ++r) {
            int node = rt * 64 + w * 16 + g * 4 + r;
            if (node < N_NODES) {
                #pragma unroll
                for (int nt = 0; nt < 16; ++nt)
                    xs[(long)node * 256 + nt * 16 + mr] = f2bf(acc[nt][r]);
                if (mr < 8) a_src[node * 8 + mr]       = acc[16][r];
                else        a_dst[node * 8 + (mr - 8)] = acc[16][r];
            }
        }
    }
}

// ---------- K4: allocate CSR segments (order-free) via wave scan ----------
__global__ __launch_bounds__(256) void k4_alloc(const int* __restrict__ counts,
                                                int* __restrict__ starts,
                                                int* __restrict__ cursor,
                                                int* __restrict__ gcur) {
    int n = blockIdx.x * 256 + threadIdx.x;
    int c = (n < N_NODES) ? counts[n] : 0;
    int incl = c;
    #pragma unroll
    for (int off = 1; off < 64; off <<= 1) {
        int u = __shfl_up(incl, off);
        if ((threadIdx.x & 63) >= off) incl += u;
    }
    int total = __shfl(incl, 63);
    int wavebase = 0;
    if ((threadIdx.x & 63) == 63) wavebase = atomicAdd(gcur, total);
    wavebase = __shfl(wavebase, 63);
    if (n < N_NODES) {
        int st = wavebase + incl - c;
        starts[n] = st;
        cursor[n] = st;
    }
}

// ---------- K25: fused a_edge dot + logits + exp + scatter {w[8], src} to CSR ----------
__global__ __launch_bounds__(256) void k25_fused(const float4* __restrict__ edge_attr4,
        const float* __restrict__ We_fold,
        const int* __restrict__ src, const int* __restrict__ dst,
        const float* __restrict__ a_src, const float* __restrict__ a_dst,
        int* __restrict__ cursor,
        float* __restrict__ w_perm, int* __restrict__ src_perm) {
    __shared__ float se[32 * 65];
    __shared__ float sf[512];
    __shared__ int s_src[32], s_dst[32], s_pos[32];
    int t = threadIdx.x;
    long ebase = (long)blockIdx.x * 32;
    for (int i = t; i < 512; i += 256) sf[i] = We_fold[i];
    for (int i = t; i < 512; i += 256) {
        float4 v = edge_attr4[ebase * 16 + i];
        int e = i >> 4, d4 = (i & 15) * 4;
        float* dp = &se[e * 65 + d4];
        dp[0] = v.x; dp[1] = v.y; dp[2] = v.z; dp[3] = v.w;
    }
    if (t < 32) {
        int e = ebase + t;
        int d = dst[e];
        s_src[t] = src[e];
        s_dst[t] = d;
        s_pos[t] = atomicAdd(&cursor[d], 1);
    }
    __syncthreads();
    int e = t >> 3, h = t & 7;
    float s = 0.f;
    #pragma unroll
    for (int d0 = 0; d0 < EDGE_DIM; ++d0)
        s = fmaf(se[e * 65 + d0], sf[d0 * 8 + h], s);
    int sn = s_src[e], dn = s_dst[e];
    float v = a_src[sn * 8 + h] + a_dst[dn * 8 + h] + s;
    v = (v > 0.f) ? v : NEG_SLOPE * v;
    float w = __expf(v);
    int pos = s_pos[e];
    w_perm[(size_t)pos * 8 + h] = w;
    if (h == 0) src_perm[pos] = sn;
}

// ---------- K6: wave-per-node streaming normalize + aggregation ----------
__global__ __launch_bounds__(256) void k6_wave(
    const int* __restrict__ starts, const int* __restrict__ counts,
    const float* __restrict__ w_perm, const int* __restrict__ src_perm,
    const unsigned short* __restrict__ xs, const float* __restrict__ bias,
    float* __restrict__ out) {
    int lane = threadIdx.x & 63;
    int n = blockIdx.x * 4 + (threadIdx.x >> 6);
    if (n >= N_NODES) return;
    int start = starts[n], cnt = counts[n];
    int j = lane >> 3;        // weight-slot this lane loads
    int hq = lane >> 3;       // head of this lane's 4 output cols (c = lane*4+k)

    float acc0 = 0.f, acc1 = 0.f, acc2 = 0.f, acc3 = 0.f;
    float psum = 0.f;
    for (int base = 0; base < cnt; base += 8) {
        int nk = cnt - base; if (nk > 8) nk = 8;
        float wv = w_perm[(size_t)(start + base) * 8 + lane];   // 256B coalesced
        if (j >= nk) wv = 0.f;
        psum += wv;
        int sv = src_perm[start + base + (lane & 7)];
        #pragma unroll
        for (int jj = 0; jj < 8; ++jj) {
            int s = __shfl(sv, jj);
            s = (jj < nk) ? s : 0;
            float w = __shfl(wv, jj * 8 + hq);
            ushort4 xv = *(const ushort4*)&xs[(size_t)s * 256 + lane * 4];
            acc0 = fmaf(w, bf2f(xv.x), acc0);
            acc1 = fmaf(w, bf2f(xv.y), acc1);
            acc2 = fmaf(w, bf2f(xv.z), acc2);
            acc3 = fmaf(w, bf2f(xv.w), acc3);
        }
    }
    // reduce psum over lanes with same (lane&7) -> per-head denominators
    psum += __shfl_xor(psum, 8);
    psum += __shfl_xor(psum, 16);
    psum += __shfl_xor(psum, 32);
    float denom = __shfl(psum, hq);       // lane hq holds head hq's sum
    float rinv = 1.0f / (denom + 1e-16f);
    float4 bv = *(const float4*)&bias[lane * 4];
    float4 o;
    o.x = acc0 * rinv + bv.x;
    o.y = acc1 * rinv + bv.y;
    o.z = acc2 * rinv + bv.z;
    o.w = acc3 * rinv + bv.w;
    *(float4*)&out[(size_t)n * 256 + lane * 4] = o;
}

extern "C" void kernel_launch(void* const* d_in, const int* in_sizes, int n_in,
                              void* d_out, int out_size, void* d_ws, size_t ws_size,
                              hipStream_t stream) {
    const float* x         = (const float*)d_in[0];
    const int*   ei        = (const int*)d_in[1];   // [2,E]: src = ei, dst = ei+E
    const float* edge_attr = (const float*)d_in[2];
    const float* W         = (const float*)d_in[3];
    const float* att_src   = (const float*)d_in[4];
    const float* att_dst   = (const float*)d_in[5];
    const float* W_edge    = (const float*)d_in[6];
    const float* att_edge  = (const float*)d_in[7];
    const float* bias      = (const float*)d_in[8];
    float* out = (float*)d_out;

    const int* e_src = ei;
    const int* e_dst = ei + E_EDGES;

    char* p = (char*)d_ws;
    unsigned short* xs = (unsigned short*)p; p += (size_t)N_NODES * HC * 2;    // 25.6 MB
    float* a_src   = (float*)p; p += (size_t)N_NODES * 8 * 4;                  // 1.6 MB
    float* a_dst   = (float*)p; p += (size_t)N_NODES * 8 * 4;                  // 1.6 MB
    float* w_perm  = (float*)p; p += (size_t)E_EDGES * 8 * 4 + 256;            // 25.6 MB (+pad)
    int* src_perm  = (int*)p;   p += (size_t)E_EDGES * 4 + 256;                // 3.2 MB (+pad)
    unsigned short* W_T  = (unsigned short*)p; p += 32768 * 2;                 // 64 KB
    unsigned short* WaT  = (unsigned short*)p; p += 2048 * 2;                  // 4 KB
    float* We_fold = (float*)p; p += 512 * 4;                                  // 2 KB
    int* counts    = (int*)p;   p += 200192;
    int* starts    = (int*)p;   p += 200192;
    int* cursor    = (int*)p;   p += 200192;
    int* gcur      = (int*)p;   p += 256;

    hipLaunchKernelGGL(k_pre, dim3(196), dim3(256), 0, stream,
                       W, att_src, att_dst, W_edge, att_edge, W_T, WaT, We_fold, counts, gcur);
    hipLaunchKernelGGL(k_hist, dim3(E_EDGES / 256), dim3(256), 0, stream, e_dst, counts);
    hipLaunchKernelGGL(k1_mfma, dim3(K1_GRID), dim3(256), 0, stream,
                       x, W_T, WaT, xs, a_src, a_dst);
    hipLaunchKernelGGL(k4_alloc, dim3(196), dim3(256), 0, stream,
                       counts, starts, cursor, gcur);
    hipLaunchKernelGGL(k25_fused, dim3(E_EDGES / 32), dim3(256), 0, stream,
                       (const float4*)edge_attr, We_fold, e_src, e_dst,
                       a_src, a_dst, cursor, w_perm, src_perm);
    hipLaunchKernelGGL(k6_wave, dim3(N_NODES / 4), dim3(256), 0, stream,
                       starts, counts, w_perm, src_perm, xs, bias, out);
}